// Round 1
// baseline (257.209 us; speedup 1.0000x reference)
//
#include <hip/hip_runtime.h>
#include <hip/hip_bf16.h>

// SOM step: M=128, N=128, DIM=2048, NITER=1000, ALPHA=0.3, SIGMA=64, eps=1e-6
// ROWS = M*N = 16384; weights = 16384 x 2048 fp32 (128 MiB).
//
// Pass 1: per-row dist^2 of (x - w + eps), global argmin (first-min tiebreak)
//         via atomicMin on key = (float_bits(d2) << 32) | row.
// Pass 2: out = w + rate(row) * (x - w), rate = alpha_op*exp(-grid_d2/sigma_op^2).
// locations input is the row-major meshgrid -> (row>>7, row&127); never loaded.
// bmu_loc_1d in the reference is dead code (not part of the output).

#define ROWS 16384
#define DIMV 512          // 2048 floats = 512 float4
#define EPS 1e-6f

__global__ __launch_bounds__(256) void som_argmin(const float* __restrict__ x,
                                                  const float* __restrict__ w,
                                                  unsigned long long* __restrict__ key) {
    const int lane = threadIdx.x & 63;
    const int wid  = threadIdx.x >> 6;                 // wave id in block, 0..3
    const int gw   = blockIdx.x * 4 + wid;             // global wave id
    const int nwaves = gridDim.x * 4;

    // x fragment held in registers: lane reads float4 index lane + i*64
    float4 xv[8];
#pragma unroll
    for (int i = 0; i < 8; ++i)
        xv[i] = ((const float4*)x)[lane + i * 64];

    unsigned long long best = ~0ULL;

    for (int row = gw; row < ROWS; row += nwaves) {
        const float4* wr = (const float4*)(w + (size_t)row * 2048);
        float acc = 0.0f;
#pragma unroll
        for (int i = 0; i < 8; ++i) {
            float4 wv = wr[lane + i * 64];
            float d0 = xv[i].x - wv.x + EPS;
            float d1 = xv[i].y - wv.y + EPS;
            float d2 = xv[i].z - wv.z + EPS;
            float d3 = xv[i].w - wv.w + EPS;
            acc += d0 * d0 + d1 * d1 + d2 * d2 + d3 * d3;
        }
        // butterfly reduce across 64 lanes (all lanes end with the sum)
#pragma unroll
        for (int off = 32; off > 0; off >>= 1)
            acc += __shfl_xor(acc, off);

        unsigned long long k =
            ((unsigned long long)__float_as_uint(acc) << 32) | (unsigned)row;
        best = best < k ? best : k;
    }

    __shared__ unsigned long long sk[4];
    if (lane == 0) sk[wid] = best;
    __syncthreads();
    if (threadIdx.x == 0) {
        unsigned long long b0 = sk[0] < sk[1] ? sk[0] : sk[1];
        unsigned long long b1 = sk[2] < sk[3] ? sk[2] : sk[3];
        unsigned long long b  = b0 < b1 ? b0 : b1;
        atomicMin(key, b);   // device-scope by default
    }
}

__global__ __launch_bounds__(256) void som_update(const float* __restrict__ x,
                                                  const float* __restrict__ w,
                                                  const unsigned long long* __restrict__ key,
                                                  const int* __restrict__ itp,
                                                  float* __restrict__ out) {
    const int lane = threadIdx.x & 63;
    const int wid  = threadIdx.x >> 6;
    const int gw   = blockIdx.x * 4 + wid;
    const int nwaves = gridDim.x * 4;

    const int bmu = (int)(unsigned)(*key & 0xFFFFFFFFULL);
    const float bi = (float)(bmu >> 7);
    const float bj = (float)(bmu & 127);

    const int it = *itp;                       // value small; low 32 bits suffice
    const float lr       = 1.0f - (float)it / 1000.0f;
    const float alpha_op = 0.3f * lr;
    const float sigma_op = 64.0f * lr;
    const float s2       = sigma_op * sigma_op;

    float4 xv[8];
#pragma unroll
    for (int i = 0; i < 8; ++i)
        xv[i] = ((const float4*)x)[lane + i * 64];

    for (int row = gw; row < ROWS; row += nwaves) {
        const float di = (float)(row >> 7) - bi;
        const float dj = (float)(row & 127) - bj;
        const float gd2 = di * di + dj * dj;
        const float rate = alpha_op * expf(-(gd2 / s2));   // wave-uniform

        const float4* wr = (const float4*)(w + (size_t)row * 2048);
        float4* orow     = (float4*)(out + (size_t)row * 2048);
#pragma unroll
        for (int i = 0; i < 8; ++i) {
            float4 wv = wr[lane + i * 64];
            float4 o;
            o.x = wv.x + rate * (xv[i].x - wv.x);
            o.y = wv.y + rate * (xv[i].y - wv.y);
            o.z = wv.z + rate * (xv[i].z - wv.z);
            o.w = wv.w + rate * (xv[i].w - wv.w);
            orow[lane + i * 64] = o;
        }
    }
}

extern "C" void kernel_launch(void* const* d_in, const int* in_sizes, int n_in,
                              void* d_out, int out_size, void* d_ws, size_t ws_size,
                              hipStream_t stream) {
    const float* x = (const float*)d_in[0];
    const float* w = (const float*)d_in[1];
    // d_in[2] = locations: row-major meshgrid, recomputed analytically; unused.
    const int* itp = (const int*)d_in[3];
    float* out = (float*)d_out;
    unsigned long long* key = (unsigned long long*)d_ws;

    // seed the argmin key with all-ones (don't rely on 0xAA poison)
    hipMemsetAsync(d_ws, 0xFF, sizeof(unsigned long long), stream);

    som_argmin<<<1024, 256, 0, stream>>>(x, w, key);
    som_update<<<1024, 256, 0, stream>>>(x, w, key, itp, out);
}